// Round 10
// baseline (160.135 us; speedup 1.0000x reference)
//
#include <hip/hip_runtime.h>

// CompiledLogicNet, pair-split: TWO blocks per u32 batch-column (32 samples),
// each computes half the gates (halved per-CU LDS gather ops) but holds the
// FULL state in LDS; halves are exchanged per layer via global staging
// (parity double-buffered) + device-scope flag handshake (XCD-safe).
// 256 blocks x 1024 threads = all 256 CUs engaged (1 block/CU @ 134KB LDS).
// Deadlock-free: pairs only wait on each other; non-resident partners always
// get dispatched as other pairs complete.
// NOTE: bank-balancing preps (R5 serial-LDS, R7 ballot-search) both regressed
// (+23, +8 us) -- prep cost exceeds any gather-conflict win. Do not revisit.

#define NIN   784
#define WIDTH 16000
#define SW    16384    // padded width (16 * TPB)
#define NH    4
#define NC    10
#define GPC   1600     // gates per class
#define NBLK  256      // 128 columns x 2 halves
#define TPB   1024
#define HALF  8192     // gates per half (SW/2)

typedef unsigned int u32;

// ---------------------------------------------------------------------------
// Pack (idx_a, idx_b, neg) -> desc[l][g] = ia | ib<<14 | na<<28 | nb<<29,
// padded to SW per layer (pad gates: a=b=0, no neg -> harmless).
__global__ void desc_kernel(const int* __restrict__ ia0, const int* __restrict__ ib0,
                            const int* __restrict__ n0,
                            const int* __restrict__ ia, const int* __restrict__ ib,
                            const int* __restrict__ n, u32* __restrict__ desc) {
    int t = blockIdx.x * blockDim.x + threadIdx.x;
    if (t >= (NH + 1) * SW) return;
    int l = t >> 14;          // t / SW
    int g = t & (SW - 1);     // t % SW
    u32 d = 0;
    if (g < WIDTH) {
        int a, b, na, nb;
        if (l == 0) { a = ia0[g]; b = ib0[g]; na = n0[2 * g]; nb = n0[2 * g + 1]; }
        else {
            int o = (l - 1) * WIDTH + g;
            a = ia[o]; b = ib[o]; na = n[2 * o]; nb = n[2 * o + 1];
        }
        d = (u32)a | ((u32)b << 14) | (na ? (1u << 28) : 0u) | (nb ? (1u << 29) : 0u);
    }
    desc[t] = d;
}

// ---------------------------------------------------------------------------
__launch_bounds__(TPB, 4)
__global__ void net_kernel(const int* __restrict__ x, const u32* __restrict__ desc,
                           int* __restrict__ out, u32* __restrict__ stage,
                           u32* __restrict__ flags) {
    __shared__ __align__(16) u32 xw[NIN];
    __shared__ __align__(16) u32 bufA[SW];
    __shared__ __align__(16) u32 bufB[SW];

    int bid = blockIdx.x;
    int w = bid >> 1;          // column
    int h = bid & 1;           // half: gates [h*8192, h*8192+8192)
    int t = threadIdx.x;

    u32* flag_own = flags + 2 * w + h;
    u32* flag_par = flags + 2 * w + (1 - h);

    // prefetch layer-0 descriptors for own half (2 x dwordx4)
    uint4 dreg[2];
    {
        const uint4* d0 = (const uint4*)desc;
        dreg[0] = d0[t + (2 * h + 0) * TPB];
        dreg[1] = d0[t + (2 * h + 1) * TPB];
    }

    // ---- pack: xw[i] bit r = x[w*32+r][i] (coalesced along i) ----
    if (t < NIN) {
        const int* base = x + (size_t)(w * 32) * NIN + t;
        u32 acc = 0;
#pragma unroll
        for (int r = 0; r < 32; ++r)
            acc |= (base[(size_t)r * NIN] != 0 ? 1u : 0u) << r;
        xw[t] = acc;
    }
    __syncthreads();

    // ---- 5 layers, ping-pong LDS; own half computed, partner half exchanged ----
    u32* cur = xw;
#pragma unroll
    for (int l = 0; l <= NH; ++l) {
        u32* dst = (l & 1) ? bufB : bufA;   // A,B,A,B,A -> result in bufA
        uint4 dn[2];
        if (l < NH) {
            const uint4* dq = (const uint4*)(desc + (size_t)(l + 1) * SW);
            dn[0] = dq[t + (2 * h + 0) * TPB];
            dn[1] = dq[t + (2 * h + 1) * TPB];
        }
        // Phase 1: all 8 a-reads, then all 8 b-reads
        u32 av[8], bv[8];
#pragma unroll
        for (int jl = 0; jl < 2; ++jl) {
            av[4 * jl + 0] = cur[dreg[jl].x & 0x3FFFu];
            av[4 * jl + 1] = cur[dreg[jl].y & 0x3FFFu];
            av[4 * jl + 2] = cur[dreg[jl].z & 0x3FFFu];
            av[4 * jl + 3] = cur[dreg[jl].w & 0x3FFFu];
        }
#pragma unroll
        for (int jl = 0; jl < 2; ++jl) {
            bv[4 * jl + 0] = cur[(dreg[jl].x >> 14) & 0x3FFFu];
            bv[4 * jl + 1] = cur[(dreg[jl].y >> 14) & 0x3FFFu];
            bv[4 * jl + 2] = cur[(dreg[jl].z >> 14) & 0x3FFFu];
            bv[4 * jl + 3] = cur[(dreg[jl].w >> 14) & 0x3FFFu];
        }
        // Phase 2: compute; store own half to own LDS + global staging
        u32* stg = stage + (((size_t)(l & 1) * 128 + w) * 2 + h) * HALF;
#pragma unroll
        for (int jl = 0; jl < 2; ++jl) {
            u32 d0 = dreg[jl].x, d1 = dreg[jl].y, d2 = dreg[jl].z, d3 = dreg[jl].w;
            uint4 r;
            r.x = (av[4 * jl + 0] ^ (0u - ((d0 >> 28) & 1u))) & (bv[4 * jl + 0] ^ (0u - ((d0 >> 29) & 1u)));
            r.y = (av[4 * jl + 1] ^ (0u - ((d1 >> 28) & 1u))) & (bv[4 * jl + 1] ^ (0u - ((d1 >> 29) & 1u)));
            r.z = (av[4 * jl + 2] ^ (0u - ((d2 >> 28) & 1u))) & (bv[4 * jl + 2] ^ (0u - ((d2 >> 29) & 1u)));
            r.w = (av[4 * jl + 3] ^ (0u - ((d3 >> 28) & 1u))) & (bv[4 * jl + 3] ^ (0u - ((d3 >> 29) & 1u)));
            int j = 2 * h + jl;
            *(uint4*)(dst + 4 * (t + j * TPB)) = r;          // ds_write_b128
            *(uint4*)(stg + 4 * (t + jl * TPB)) = r;         // coalesced dwordx4
        }
        // handshake: publish own half, wait for partner's
        __syncthreads();   // drains vmcnt: all staging stores retired
        if (t == 0) {
            __threadfence();                                  // agent release (L2 wb)
            atomicAdd(flag_own, 1u);
            while (__hip_atomic_load(flag_par, __ATOMIC_ACQUIRE,
                                     __HIP_MEMORY_SCOPE_AGENT) < (u32)(l + 1)) {
                __builtin_amdgcn_s_sleep(2);
            }
        }
        __syncthreads();
        // pull partner half from staging into own LDS
        {
            const u32* ps = stage + (((size_t)(l & 1) * 128 + w) * 2 + (1 - h)) * HALF;
#pragma unroll
            for (int jl = 0; jl < 2; ++jl) {
                uint4 v = *(const uint4*)(ps + 4 * (t + jl * TPB));
                int j = 2 * (1 - h) + jl;
                *(uint4*)(dst + 4 * (t + j * TPB)) = v;
            }
        }
        __syncthreads();
        dreg[0] = dn[0]; dreg[1] = dn[1];
        cur = dst;
    }
    u32* res = bufA;

    // ---- GroupSum: 5 classes per half-block; wave per class, CSA + butterfly ----
    int wave = t >> 6, lane = t & 63;
    if (wave < 5) {
        int c = 5 * h + wave;
        const u32* base = res + c * GPC;
        u32 p0 = 0, p1 = 0, p2 = 0, p3 = 0, p4 = 0;
#define CSA5(VAL) { u32 cy = (VAL); u32 s; \
        s = p0; p0 = s ^ cy; cy = s & cy; \
        s = p1; p1 = s ^ cy; cy = s & cy; \
        s = p2; p2 = s ^ cy; cy = s & cy; \
        s = p3; p3 = s ^ cy; cy = s & cy; \
        s = p4; p4 = s ^ cy; }
#pragma unroll
        for (int k = 0; k < 6; ++k) {
            uint4 v = *(const uint4*)(base + 4 * lane + 256 * k);  // b128, conflict-free
            CSA5(v.x); CSA5(v.y); CSA5(v.z); CSA5(v.w);
        }
        CSA5(base[1536 + lane]);   // 25 values per lane, fits 5 planes
#undef CSA5

        // butterfly: merge 64 lanes' plane sets; planes grow 5 -> 11
        u32 pl[11];
        pl[0] = p0; pl[1] = p1; pl[2] = p2; pl[3] = p3; pl[4] = p4;
#pragma unroll
        for (int s = 0; s < 6; ++s) {
            int np = 5 + s;
            u32 q[11];
#pragma unroll
            for (int i = 0; i < 11; ++i) if (i < np) q[i] = __shfl_xor(pl[i], 1 << s, 64);
            u32 carry = 0;
#pragma unroll
            for (int i = 0; i < 11; ++i) if (i < np) {
                u32 a = pl[i], b = q[i];
                u32 xr = a ^ b;
                pl[i] = xr ^ carry;
                carry = (a & b) | (carry & xr);
            }
            pl[np] = carry;
        }

        if (lane < 32) {
            int cntv = 0;
#pragma unroll
            for (int i = 0; i < 11; ++i) cntv += (int)((pl[i] >> lane) & 1u) << i;
            out[((size_t)w * 32 + lane) * NC + c] = cntv;
        }
    }
}

// ---------------------------------------------------------------------------
extern "C" void kernel_launch(void* const* d_in, const int* in_sizes, int n_in,
                              void* d_out, int out_size, void* d_ws, size_t ws_size,
                              hipStream_t stream) {
    const int* x      = (const int*)d_in[0];  // [4096,784] 0/1
    const int* idx_a0 = (const int*)d_in[1];  // [16000]
    const int* idx_b0 = (const int*)d_in[2];  // [16000]
    const int* neg0   = (const int*)d_in[3];  // [16000,2]
    const int* idx_a  = (const int*)d_in[4];  // [4,16000]
    const int* idx_b  = (const int*)d_in[5];  // [4,16000]
    const int* neg    = (const int*)d_in[6];  // [4,16000,2]
    int* out = (int*)d_out;                   // [4096,10]

    char* ws    = (char*)d_ws;
    u32*  desc  = (u32*)ws;                       // 327,680 B
    u32*  flags = (u32*)(ws + 327680);            // 256 u32 = 1 KB
    u32*  stage = (u32*)(ws + 327680 + 4096);     // 2*128*2*8192*4 = 16 MB

    hipMemsetAsync(flags, 0, 256 * sizeof(u32), stream);

    int ndesc = (NH + 1) * SW;
    desc_kernel<<<(ndesc + 255) / 256, 256, 0, stream>>>(
        idx_a0, idx_b0, neg0, idx_a, idx_b, neg, desc);

    net_kernel<<<NBLK, TPB, 0, stream>>>(x, desc, out, stage, flags);
}

// Round 11
// 86.222 us; speedup vs baseline: 1.8572x; 1.8572x over previous
//
#include <hip/hip_runtime.h>

// CompiledLogicNet fully fused: one block per u32 batch-column (32 samples).
// State [16384] u32 (16000 padded) in LDS, double-buffered. Gathers = LDS reads.
// Layer loop: 2-stage software pipeline over 4 gate-groups (4 gates each):
// reads for groups j,j+1 in flight while group j-? computes + ds_write_b128.
// GroupSum: one wave per class, b128 reads + CSA planes + shfl_xor butterfly.
// NOTE (do not revisit): bank-balancing preps regressed (R5 +23us serial-LDS,
// R7 +8us ballot-search); cross-block pair-split regressed (R9 +73us --
// global-staging handshake latency >> halved gather work).

#define NIN   784
#define WIDTH 16000
#define SW    16384    // padded width (16 * TPB)
#define NH    4
#define NC    10
#define GPC   1600     // gates per class
#define NBLK  128      // u32 columns: 4096 batch / 32
#define TPB   1024

typedef unsigned int u32;

// ---------------------------------------------------------------------------
// Pack (idx_a, idx_b, neg) -> desc[l][g] = ia | ib<<14 | na<<28 | nb<<29,
// padded to SW per layer (pad gates: a=b=0, no neg -> harmless).
__global__ void desc_kernel(const int* __restrict__ ia0, const int* __restrict__ ib0,
                            const int* __restrict__ n0,
                            const int* __restrict__ ia, const int* __restrict__ ib,
                            const int* __restrict__ n, u32* __restrict__ desc) {
    int t = blockIdx.x * blockDim.x + threadIdx.x;
    if (t >= (NH + 1) * SW) return;
    int l = t >> 14;          // t / SW
    int g = t & (SW - 1);     // t % SW
    u32 d = 0;
    if (g < WIDTH) {
        int a, b, na, nb;
        if (l == 0) { a = ia0[g]; b = ib0[g]; na = n0[2 * g]; nb = n0[2 * g + 1]; }
        else {
            int o = (l - 1) * WIDTH + g;
            a = ia[o]; b = ib[o]; na = n[2 * o]; nb = n[2 * o + 1];
        }
        d = (u32)a | ((u32)b << 14) | (na ? (1u << 28) : 0u) | (nb ? (1u << 29) : 0u);
    }
    desc[t] = d;
}

// ---------------------------------------------------------------------------
__launch_bounds__(TPB, 4)
__global__ void net_kernel(const int* __restrict__ x, const u32* __restrict__ desc,
                           int* __restrict__ out) {
    __shared__ __align__(16) u32 xw[NIN];
    __shared__ __align__(16) u32 bufA[SW];
    __shared__ __align__(16) u32 bufB[SW];

    int w = blockIdx.x;
    int t = threadIdx.x;

    // prefetch layer-0 descriptors (4 x dwordx4) while we pack
    uint4 dreg[4];
    {
        const uint4* d0 = (const uint4*)desc;
#pragma unroll
        for (int j = 0; j < 4; ++j) dreg[j] = d0[t + j * TPB];
    }

    // ---- pack: xw[i] bit r = x[w*32+r][i] (coalesced along i) ----
    if (t < NIN) {
        const int* base = x + (size_t)(w * 32) * NIN + t;
        u32 acc = 0;
#pragma unroll
        for (int r = 0; r < 32; ++r)
            acc |= (base[(size_t)r * NIN] != 0 ? 1u : 0u) << r;
        xw[t] = acc;
    }
    __syncthreads();

    // ---- 5 layers, ping-pong LDS; 2-stage pipelined gather/compute ----
    u32* cur = xw;
#pragma unroll
    for (int l = 0; l <= NH; ++l) {
        u32* dst = (l & 1) ? bufB : bufA;   // A,B,A,B,A -> result in bufA
        uint4 dn[4];
        if (l < NH) {
            const uint4* dq = (const uint4*)(desc + (size_t)(l + 1) * SW);
#pragma unroll
            for (int j = 0; j < 4; ++j) dn[j] = dq[t + j * TPB];
        }

        u32 av[4][4], bv[4][4];
#define READG(j) { \
        uint4 dd = dreg[j]; \
        av[j][0] = cur[dd.x & 0x3FFFu]; bv[j][0] = cur[(dd.x >> 14) & 0x3FFFu]; \
        av[j][1] = cur[dd.y & 0x3FFFu]; bv[j][1] = cur[(dd.y >> 14) & 0x3FFFu]; \
        av[j][2] = cur[dd.z & 0x3FFFu]; bv[j][2] = cur[(dd.z >> 14) & 0x3FFFu]; \
        av[j][3] = cur[dd.w & 0x3FFFu]; bv[j][3] = cur[(dd.w >> 14) & 0x3FFFu]; }
#define COMPG(j) { \
        u32 d0 = dreg[j].x, d1 = dreg[j].y, d2 = dreg[j].z, d3 = dreg[j].w; \
        uint4 r; \
        r.x = (av[j][0] ^ (0u - ((d0 >> 28) & 1u))) & (bv[j][0] ^ (0u - ((d0 >> 29) & 1u))); \
        r.y = (av[j][1] ^ (0u - ((d1 >> 28) & 1u))) & (bv[j][1] ^ (0u - ((d1 >> 29) & 1u))); \
        r.z = (av[j][2] ^ (0u - ((d2 >> 28) & 1u))) & (bv[j][2] ^ (0u - ((d2 >> 29) & 1u))); \
        r.w = (av[j][3] ^ (0u - ((d3 >> 28) & 1u))) & (bv[j][3] ^ (0u - ((d3 >> 29) & 1u))); \
        *(uint4*)(dst + 4 * (t + (j) * TPB)) = r; }

        READG(0)
        READG(1)
        READG(2)
        COMPG(0)
        READG(3)
        COMPG(1)
        COMPG(2)
        COMPG(3)
#undef READG
#undef COMPG

        __syncthreads();
#pragma unroll
        for (int j = 0; j < 4; ++j) dreg[j] = dn[j];
        cur = dst;
    }
    u32* res = bufA;

    // ---- GroupSum: one wave per class, CSA planes + shfl_xor butterfly ----
    int wave = t >> 6, lane = t & 63;
    if (wave < NC) {
        int c = wave;
        const u32* base = res + c * GPC;
        u32 p0 = 0, p1 = 0, p2 = 0, p3 = 0, p4 = 0;
#define CSA5(VAL) { u32 cy = (VAL); u32 s; \
        s = p0; p0 = s ^ cy; cy = s & cy; \
        s = p1; p1 = s ^ cy; cy = s & cy; \
        s = p2; p2 = s ^ cy; cy = s & cy; \
        s = p3; p3 = s ^ cy; cy = s & cy; \
        s = p4; p4 = s ^ cy; }
#pragma unroll
        for (int k = 0; k < 6; ++k) {
            uint4 v = *(const uint4*)(base + 4 * lane + 256 * k);  // b128, conflict-free
            CSA5(v.x); CSA5(v.y); CSA5(v.z); CSA5(v.w);
        }
        CSA5(base[1536 + lane]);   // 25 values per lane, fits 5 planes
#undef CSA5

        // butterfly: merge 64 lanes' plane sets; planes grow 5 -> 11
        u32 pl[11];
        pl[0] = p0; pl[1] = p1; pl[2] = p2; pl[3] = p3; pl[4] = p4;
#pragma unroll
        for (int s = 0; s < 6; ++s) {
            int np = 5 + s;
            u32 q[11];
#pragma unroll
            for (int i = 0; i < 11; ++i) if (i < np) q[i] = __shfl_xor(pl[i], 1 << s, 64);
            u32 carry = 0;
#pragma unroll
            for (int i = 0; i < 11; ++i) if (i < np) {
                u32 a = pl[i], b = q[i];
                u32 xr = a ^ b;
                pl[i] = xr ^ carry;
                carry = (a & b) | (carry & xr);
            }
            pl[np] = carry;
        }

        // every lane now holds the 11-plane vertical count over 1600 gates
        if (lane < 32) {
            int cntv = 0;
#pragma unroll
            for (int i = 0; i < 11; ++i) cntv += (int)((pl[i] >> lane) & 1u) << i;
            out[((size_t)w * 32 + lane) * NC + c] = cntv;
        }
    }
}

// ---------------------------------------------------------------------------
extern "C" void kernel_launch(void* const* d_in, const int* in_sizes, int n_in,
                              void* d_out, int out_size, void* d_ws, size_t ws_size,
                              hipStream_t stream) {
    const int* x      = (const int*)d_in[0];  // [4096,784] 0/1
    const int* idx_a0 = (const int*)d_in[1];  // [16000]
    const int* idx_b0 = (const int*)d_in[2];  // [16000]
    const int* neg0   = (const int*)d_in[3];  // [16000,2]
    const int* idx_a  = (const int*)d_in[4];  // [4,16000]
    const int* idx_b  = (const int*)d_in[5];  // [4,16000]
    const int* neg    = (const int*)d_in[6];  // [4,16000,2]
    int* out = (int*)d_out;                   // [4096,10]

    u32* desc = (u32*)d_ws;                   // (NH+1)*SW*4 = 327,680 B

    int ndesc = (NH + 1) * SW;
    desc_kernel<<<(ndesc + 255) / 256, 256, 0, stream>>>(
        idx_a0, idx_b0, neg0, idx_a, idx_b, neg, desc);

    net_kernel<<<NBLK, TPB, 0, stream>>>(x, desc, out);
}